// Round 18
// baseline (962.473 us; speedup 1.0000x reference)
//
#include <hip/hip_runtime.h>
#include <hip/hip_bf16.h>

#define ALPHA 1.702f
#define GLIMIT 7.0f

typedef __attribute__((ext_vector_type(4))) float f32x4;
typedef __attribute__((ext_vector_type(4))) short short4v;
typedef __attribute__((ext_vector_type(2))) short short2v;
typedef __attribute__((ext_vector_type(8))) __bf16 bf16x8;
typedef __attribute__((ext_vector_type(8))) short short8;

typedef __attribute__((address_space(3))) unsigned int as3_uint;
typedef const __attribute__((address_space(1))) unsigned int as1_uint;

__device__ __forceinline__ void async_copy16(void* lds, const void* g) {
    __builtin_amdgcn_global_load_lds((as1_uint*)g, (as3_uint*)lds, 16, 0, 0);
}

__device__ __forceinline__ short f2bf(float f) {
    unsigned u = __float_as_uint(f);
    unsigned r = (u + 0x7fffu + ((u >> 16) & 1u)) >> 16;
    return (short)r;
}

// ---------- fp32 -> bf16 straight convert (x) ----------
__global__ void cvt_bf16_kernel(const float* __restrict__ src,
                                short* __restrict__ dst, int n4) {
    int i = blockIdx.x * blockDim.x + threadIdx.x;
    if (i < n4) {
        float4 v = reinterpret_cast<const float4*>(src)[i];
        short4 o;
        o.x = f2bf(v.x); o.y = f2bf(v.y); o.z = f2bf(v.z); o.w = f2bf(v.w);
        reinterpret_cast<short4*>(dst)[i] = o;
    }
}

// ---------- fp32 [z][R][C] -> bf16 [z][C][R] transpose-convert ----------
// perm!=0: pair-split permutation within each 256-row panel of dst:
// row rloc -> (rloc&1)*128 + (rloc>>1)  (panel = [128 gate rows][128 up rows]).
__global__ void transpose_cvt(const float* __restrict__ src,
                              short* __restrict__ dst, int R, int C, int perm) {
    __shared__ float t[64][65];
    const int z  = blockIdx.z;
    const int c0 = blockIdx.x * 64;
    const int r0 = blockIdx.y * 64;
    const float* s = src + (size_t)z * R * C;
    short* d = dst + (size_t)z * R * C;
    const int tid = threadIdx.x;
#pragma unroll
    for (int i = 0; i < 16; ++i) {
        int idx = i * 256 + tid;
        int r = idx >> 6, c = idx & 63;
        t[r][c] = s[(size_t)(r0 + r) * C + c0 + c];
    }
    __syncthreads();
#pragma unroll
    for (int i = 0; i < 8; ++i) {
        int idx = i * 256 + tid;          // 2048 pairs: r 0..63, c2 0..31
        int r = idx >> 5, c2 = (idx & 31) << 1;
        int rr = c0 + r;
        int rloc = rr & 255;
        int rp = perm ? ((rr & ~255) | ((rloc & 1) << 7) | (rloc >> 1)) : rr;
        short2v o;
        o[0] = f2bf(t[c2][r]);
        o[1] = f2bf(t[c2 + 1][r]);
        *(short2v*)(d + (size_t)rp * R + r0 + c2) = o;
    }
}

// =================== 256x256 8-phase GEMM core (R5 schedule) ==========

struct Gemm1PSrc {
    const short* A; const short* B;   // A = xb + m0*2048 ; B = wgut + n0*2048
    __device__ __forceinline__ const short* operator()(int t, int h) const {
        int e = (t >> 5) & 7;
        size_t ko = (size_t)(t & 31) << 6;
        if (h & 2) return B + ((size_t)e << 23) + ((size_t)(h & 1) << 18) + ko;
        return A + ((size_t)(h & 1) << 18) + ko;
    }
};

struct Gemm2Src {
    const short* act; const short* wdt; size_t aoff, boff; int kh;
    __device__ __forceinline__ const short* operator()(int t, int h) const {
        int g = (kh << 7) + t;
        int e = (g >> 5) & 7;
        size_t ko = (size_t)(g & 31) << 6;
        if (h & 2) return wdt + ((size_t)e << 22) + boff + ((size_t)(h & 1) << 18) + ko;
        return act + ((size_t)e << 23) + aoff + ((size_t)(h & 1) << 18) + ko;
    }
};

#define PH_BAR()  __builtin_amdgcn_s_barrier()
#define PH_LGKM() do { asm volatile("s_waitcnt lgkmcnt(0)" ::: "memory"); \
                       __builtin_amdgcn_sched_barrier(0); } while (0)
#define VMW(n)    asm volatile("s_waitcnt vmcnt(" #n ")" ::: "memory")

template <int NT, int SEG, bool DRAIN, typename Src, typename Epi>
__device__ __forceinline__ void gemm_8phase(const Src& src, char* smem,
                                            f32x4 (&acc)[8][4], const Epi& epi) {
    const int tid  = threadIdx.x;
    const int lane = tid & 63;
    const int wid  = tid >> 6;
    const int wr   = wid >> 2;
    const int wcol = wid & 3;
    const int lhi  = lane >> 4;
    const int llo  = lane & 15;

    auto stage = [&](int buf, int h, const short* g) {
        char* dst = smem + buf * 65536 + h * 16384;
        {
            int c = tid, r = c >> 3, s = (c & 7) ^ (r & 7);
            async_copy16(dst + c * 16, g + (size_t)r * 2048 + s * 8);
        }
        {
            int c = tid + 512, r = c >> 3, s = (c & 7) ^ (r & 7);
            async_copy16(dst + c * 16, g + (size_t)r * 2048 + s * 8);
        }
    };
    auto ldfrag = [&](int buf, int h, int row, int slot) {
        return *(const bf16x8*)(smem + buf * 65536 + h * 16384 + row * 128 +
                                ((slot ^ (row & 7)) << 4));
    };

    stage(0, 0, src(0, 0)); stage(0, 2, src(0, 2));
    stage(0, 3, src(0, 3)); stage(0, 1, src(0, 1));
    stage(1, 0, src(1, 0)); stage(1, 2, src(1, 2)); stage(1, 3, src(1, 3));
    VMW(8);
    PH_BAR();

    bf16x8 a[4][2], b[4][2];
#pragma unroll
    for (int n = 0; n < 2; ++n) {
        int row = wcol * 32 + n * 16 + llo;
        b[n][0] = ldfrag(0, 2, row, lhi);
        b[n][1] = ldfrag(0, 2, row, 4 + lhi);
    }

    for (int t = 0; t < NT; ++t) {
        const int cur = t & 1, nxt = cur ^ 1;
        // P0
#pragma unroll
        for (int m = 0; m < 4; ++m) {
            int row = wr * 64 + m * 16 + llo;
            a[m][0] = ldfrag(cur, 0, row, lhi);
            a[m][1] = ldfrag(cur, 0, row, 4 + lhi);
        }
        if (t + 1 < NT) stage(nxt, 1, src(t + 1, 1));
        PH_BAR(); PH_LGKM();
        __builtin_amdgcn_s_setprio(1);
#pragma unroll
        for (int m = 0; m < 4; ++m)
#pragma unroll
            for (int n = 0; n < 2; ++n)
#pragma unroll
                for (int ks = 0; ks < 2; ++ks)
                    acc[m][n] = __builtin_amdgcn_mfma_f32_16x16x32_bf16(
                        a[m][ks], b[n][ks], acc[m][n], 0, 0, 0);
        __builtin_amdgcn_s_setprio(0);
        PH_BAR();
        // P1
#pragma unroll
        for (int n = 0; n < 2; ++n) {
            int row = wcol * 32 + n * 16 + llo;
            b[2 + n][0] = ldfrag(cur, 3, row, lhi);
            b[2 + n][1] = ldfrag(cur, 3, row, 4 + lhi);
        }
        if (t + 2 < NT) { stage(cur, 0, src(t + 2, 0)); VMW(10); }
        else if (t + 1 < NT) { VMW(8); }
        else { VMW(0); }
        PH_BAR(); PH_LGKM();
        __builtin_amdgcn_s_setprio(1);
#pragma unroll
        for (int m = 0; m < 4; ++m)
#pragma unroll
            for (int n = 2; n < 4; ++n)
#pragma unroll
                for (int ks = 0; ks < 2; ++ks)
                    acc[m][n] = __builtin_amdgcn_mfma_f32_16x16x32_bf16(
                        a[m][ks], b[n][ks], acc[m][n], 0, 0, 0);
        __builtin_amdgcn_s_setprio(0);
        PH_BAR();
        // P2
#pragma unroll
        for (int m = 0; m < 4; ++m) {
            int row = wr * 64 + m * 16 + llo;
            a[m][0] = ldfrag(cur, 1, row, lhi);
            a[m][1] = ldfrag(cur, 1, row, 4 + lhi);
        }
        if (t + 2 < NT) stage(cur, 2, src(t + 2, 2));
        PH_BAR(); PH_LGKM();
        __builtin_amdgcn_s_setprio(1);
#pragma unroll
        for (int m = 0; m < 4; ++m)
#pragma unroll
            for (int n = 0; n < 2; ++n)
#pragma unroll
                for (int ks = 0; ks < 2; ++ks)
                    acc[4 + m][n] = __builtin_amdgcn_mfma_f32_16x16x32_bf16(
                        a[m][ks], b[n][ks], acc[4 + m][n], 0, 0, 0);
        __builtin_amdgcn_s_setprio(0);
        PH_BAR();
        // P3
        if (t + 2 < NT) { stage(cur, 3, src(t + 2, 3)); VMW(8); }
        else if (t + 1 < NT) { VMW(2); }
        else { VMW(0); }
        PH_BAR(); PH_LGKM();
        __builtin_amdgcn_s_setprio(1);
        if (t + 1 < NT) {
#pragma unroll
            for (int n = 0; n < 2; ++n) {
                int row = wcol * 32 + n * 16 + llo;
                b[n][0] = ldfrag(nxt, 2, row, lhi);
                b[n][1] = ldfrag(nxt, 2, row, 4 + lhi);
            }
        }
#pragma unroll
        for (int m = 0; m < 4; ++m)
#pragma unroll
            for (int n = 2; n < 4; ++n)
#pragma unroll
                for (int ks = 0; ks < 2; ++ks)
                    acc[4 + m][n] = __builtin_amdgcn_mfma_f32_16x16x32_bf16(
                        a[m][ks], b[n][ks], acc[4 + m][n], 0, 0, 0);
        __builtin_amdgcn_s_setprio(0);
        PH_BAR();
        if (((t + 1) & (SEG - 1)) == 0) {
            epi(t / SEG, acc);
            if (t + 1 < NT) {
                if (DRAIN) { VMW(0); }
#pragma unroll
                for (int m = 0; m < 8; ++m)
#pragma unroll
                    for (int n = 0; n < 4; ++n)
                        acc[m][n] = (f32x4){0.f, 0.f, 0.f, 0.f};
            }
        }
    }
}

// ---------- GEMM1 (persistent, R5 orientation, shfl-transpose epilogue) -------
// A = xb (tokens), B = pair-permuted Wgu (B0 half = gate, B1 half = up; GEGLU
// is lane-local). Epilogue: per (m,n) the 4 lanes lbase..lbase+3 hold a 4x4
// (row x col) block; 3-round shfl rotation transposes it -> each lane stores
// one row x 4 consecutive dcols as short4 (16 nt stores, no LDS, no barriers).
__global__ __launch_bounds__(512, 2) void gemm1_main(
    const short* __restrict__ xb, const short* __restrict__ wgut,
    const float* __restrict__ bias, const float* __restrict__ rwp,
    short* __restrict__ act) {
    __shared__ __align__(16) char smem[131072];
    __shared__ float rws2[2048];   // [row 0..255][e 0..7]
    __shared__ float bias2[2048];  // [e 0..7][col-in-panel 0..255]
    const int bid = blockIdx.x;
    const int xcd = bid & 7, j = bid >> 3;
    const int n0 = (((xcd << 1) + (j >> 4)) << 8);   // wgut panel (2/XCD)
    const int m0 = ((j & 15) << 8);                  // token tile (16/XCD)
    const int tid  = threadIdx.x;
    const int lane = tid & 63;
    const int wid  = tid >> 6;
    const int wr = wid >> 2, wcol = wid & 3;
    const int lhi = lane >> 4, llo = lane & 15;
    const int llo4 = lane & 3;
    const int lbase = lane & ~3;

    ((float4*)rws2)[tid] = ((const float4*)(rwp + (size_t)m0 * 8))[tid];
    {
        int idx = tid << 2;
        int ei = idx >> 8, c = idx & 255;
        ((float4*)bias2)[tid] =
            *(const float4*)(bias + (size_t)ei * 4096 + n0 + c);
    }

    f32x4 acc[8][4];
#pragma unroll
    for (int m = 0; m < 8; ++m)
#pragma unroll
        for (int n = 0; n < 4; ++n) acc[m][n] = (f32x4){0.f, 0.f, 0.f, 0.f};

    Gemm1PSrc src{ xb + (size_t)m0 * 2048, wgut + (size_t)n0 * 2048 };
    const int a0 = n0 >> 1;

    auto epi = [&](int s, f32x4 (&ac)[8][4]) {
        int e = s & 7;
        short* acte = act + ((size_t)e << 23);
        float bg[2], bu[2];
#pragma unroll
        for (int n = 0; n < 2; ++n) {
            int acol = wcol * 32 + n * 16 + llo;
            bg[n] = bias2[(e << 8) + 2 * acol];
            bu[n] = bias2[(e << 8) + 2 * acol + 1];
        }
#pragma unroll
        for (int m = 0; m < 8; ++m) {
            int rowb_l = (m >> 2) * 128 + wr * 64 + (m & 3) * 16 + (lhi << 2);
#pragma unroll
            for (int n = 0; n < 2; ++n) {
                // lane-local GEGLU on original layout (rows rowb_l+q, col acol)
                float v[4];
#pragma unroll
                for (int q = 0; q < 4; ++q) {
                    float g = ac[m][n][q] + bg[n];
                    float u = ac[m][n + 2][q] + bu[n];
                    g = fminf(g, GLIMIT);
                    u = fmaxf(fminf(u, GLIMIT), -GLIMIT);
                    float glu = g / (1.f + __expf(-ALPHA * g));
                    v[q] = (u + 1.f) * glu * rws2[(rowb_l + q) * 8 + e];
                }
                // 4x4 transpose across lanes lbase..lbase+3 (3 real shfls)
                float o[4];
#pragma unroll
                for (int k = 0; k < 4; ++k) {
                    float sv = v[(llo4 + 4 - k) & 3];
                    o[(llo4 + k) & 3] = __shfl(sv, lbase + ((llo4 + k) & 3));
                }
                int row = m0 + rowb_l + llo4;
                int col = a0 + wcol * 32 + n * 16 + (llo & 12);
                short4v ov;
#pragma unroll
                for (int q = 0; q < 4; ++q) ov[q] = f2bf(o[q]);
                __builtin_nontemporal_store(
                    ov, (short4v*)(acte + (size_t)row * 2048 + col));
            }
        }
    };
    gemm_8phase<256, 32, true>(src, smem, acc, epi);
}

// ---------- GEMM2: split-K over experts; kh=0 -> out, kh=1 -> partial ----------
__global__ __launch_bounds__(512, 2) void gemm2_8ph(
    const short* __restrict__ act, const short* __restrict__ wdt,
    float* __restrict__ out, float* __restrict__ part) {
    __shared__ __align__(16) char smem[131072];
    const int kh = blockIdx.z;
    int flat = blockIdx.x + (blockIdx.y << 3);
    int swz = (flat & 7) * 16 + (flat >> 3);
    const int n0 = (swz & 7) * 256;
    const int m0 = (swz >> 3) * 256;
    const int tid  = threadIdx.x;
    const int lane = tid & 63;
    const int wid  = tid >> 6;
    const int wr = wid >> 2, wcol = wid & 3;

    f32x4 acc[8][4];
#pragma unroll
    for (int m = 0; m < 8; ++m)
#pragma unroll
        for (int n = 0; n < 4; ++n) acc[m][n] = (f32x4){0.f, 0.f, 0.f, 0.f};

    Gemm2Src src{ act, wdt, (size_t)m0 * 2048, (size_t)n0 * 2048, kh };
    float* dst = (kh == 0) ? out : part;

    auto epi = [&](int, f32x4 (&ac)[8][4]) {
#pragma unroll
        for (int m = 0; m < 8; ++m) {
            int row = m0 + (m >> 2) * 128 + wr * 64 + (m & 3) * 16 + ((lane >> 4) << 2);
#pragma unroll
            for (int n = 0; n < 4; ++n) {
                int col = n0 + (n >> 1) * 128 + wcol * 32 + (n & 1) * 16 + (lane & 15);
#pragma unroll
                for (int q = 0; q < 4; ++q)
                    dst[(size_t)(row + q) * 2048 + col] = ac[m][n][q];
            }
        }
    };
    gemm_8phase<128, 128, false>(src, smem, acc, epi);
}

// ---------- reduce: out += partial + sum_e rw[t,e]*bd[e,h] ----------
__global__ __launch_bounds__(256) void reduce_bias(
    const float* __restrict__ p1, const float* __restrict__ rw,
    const float* __restrict__ bd, float* __restrict__ out) {
    const int t = blockIdx.x;
    const int tid = threadIdx.x;
    float rwv[8];
#pragma unroll
    for (int e = 0; e < 8; ++e) rwv[e] = rw[(size_t)t * 8 + e];
    size_t base = (size_t)t * 2048;
#pragma unroll
    for (int i = 0; i < 2; ++i) {
        int h = (tid + i * 256) * 4;
        f32x4 o = *(const f32x4*)(out + base + h);
        f32x4 p = *(const f32x4*)(p1 + base + h);
        o += p;
#pragma unroll
        for (int e = 0; e < 8; ++e) {
            f32x4 bb = *(const f32x4*)(bd + e * 2048 + h);
            o += rwv[e] * bb;
        }
        *(f32x4*)(out + base + h) = o;
    }
}

extern "C" void kernel_launch(void* const* d_in, const int* in_sizes, int n_in,
                              void* d_out, int out_size, void* d_ws, size_t ws_size,
                              hipStream_t stream) {
    const float* x   = (const float*)d_in[0];
    const float* wgu = (const float*)d_in[1];
    const float* bgu = (const float*)d_in[2];
    const float* wd  = (const float*)d_in[3];
    const float* bd  = (const float*)d_in[4];
    const float* rw  = (const float*)d_in[5];
    float* out = (float*)d_out;

    char* ws = (char*)d_ws;
    short* xb   = (short*)(ws);
    short* wgut = (short*)(ws + 16777216);
    float* p1   = (float*)(ws + 16777216);   // aliases wgut (dead after gemm1)
    short* wdt  = (short*)(ws + 150994944);
    short* actb = (short*)(ws + 218103808);

    cvt_bf16_kernel<<<8192, 256, 0, stream>>>(x, xb, 2097152);
    transpose_cvt<<<dim3(64, 32, 8), 256, 0, stream>>>(wgu, wgut, 2048, 4096, 1);
    transpose_cvt<<<dim3(32, 32, 8), 256, 0, stream>>>(wd, wdt, 2048, 2048, 0);
    gemm1_main<<<256, 512, 0, stream>>>(xb, wgut, bgu, rw, actb);
    gemm2_8ph<<<dim3(8, 16, 2), 512, 0, stream>>>(actb, wdt, out, p1);
    reduce_bias<<<4096, 256, 0, stream>>>(p1, rw, bd, out);
}

// Round 19
// 887.948 us; speedup vs baseline: 1.0839x; 1.0839x over previous
//
#include <hip/hip_runtime.h>
#include <hip/hip_bf16.h>

#define ALPHA 1.702f
#define GLIMIT 7.0f

typedef __attribute__((ext_vector_type(4))) float f32x4;
typedef __attribute__((ext_vector_type(4))) short short4v;
typedef __attribute__((ext_vector_type(2))) short short2v;
typedef __attribute__((ext_vector_type(8))) __bf16 bf16x8;
typedef __attribute__((ext_vector_type(8))) short short8;

typedef __attribute__((address_space(3))) unsigned int as3_uint;
typedef const __attribute__((address_space(1))) unsigned int as1_uint;

__device__ __forceinline__ void async_copy16(void* lds, const void* g) {
    __builtin_amdgcn_global_load_lds((as1_uint*)g, (as3_uint*)lds, 16, 0, 0);
}

__device__ __forceinline__ short f2bf(float f) {
    unsigned u = __float_as_uint(f);
    unsigned r = (u + 0x7fffu + ((u >> 16) & 1u)) >> 16;
    return (short)r;
}

// ---------- fp32 -> bf16 straight convert (x) ----------
__global__ void cvt_bf16_kernel(const float* __restrict__ src,
                                short* __restrict__ dst, int n4) {
    int i = blockIdx.x * blockDim.x + threadIdx.x;
    if (i < n4) {
        float4 v = reinterpret_cast<const float4*>(src)[i];
        short4 o;
        o.x = f2bf(v.x); o.y = f2bf(v.y); o.z = f2bf(v.z); o.w = f2bf(v.w);
        reinterpret_cast<short4*>(dst)[i] = o;
    }
}

// ---------- fp32 [z][R][C] -> bf16 [z][C][R] transpose-convert ----------
// perm!=0: pair-split permutation within each 256-row panel of dst:
// row rloc -> (rloc&1)*128 + (rloc>>1).
// Writes vectorized as short2 (each thread covers 2 consecutive dst cols).
__global__ void transpose_cvt(const float* __restrict__ src,
                              short* __restrict__ dst, int R, int C, int perm) {
    __shared__ float t[64][65];
    const int z  = blockIdx.z;
    const int c0 = blockIdx.x * 64;
    const int r0 = blockIdx.y * 64;
    const float* s = src + (size_t)z * R * C;
    short* d = dst + (size_t)z * R * C;
    const int tid = threadIdx.x;
#pragma unroll
    for (int i = 0; i < 16; ++i) {
        int idx = i * 256 + tid;
        int r = idx >> 6, c = idx & 63;
        t[r][c] = s[(size_t)(r0 + r) * C + c0 + c];
    }
    __syncthreads();
#pragma unroll
    for (int i = 0; i < 8; ++i) {
        int idx = i * 256 + tid;          // 2048 pairs: r 0..63, c2 0..31
        int r = idx >> 5, c2 = (idx & 31) << 1;
        int rr = c0 + r;
        int rloc = rr & 255;
        int rp = perm ? ((rr & ~255) | ((rloc & 1) << 7) | (rloc >> 1)) : rr;
        short2v o;
        o[0] = f2bf(t[c2][r]);
        o[1] = f2bf(t[c2 + 1][r]);
        *(short2v*)(d + (size_t)rp * R + r0 + c2) = o;
    }
}

// =================== 256x256 8-phase GEMM core (R11 state) ==========

// GEMM1-T: A = permuted Wgu (M = gate_up rows, e-dependent), B = x (N = tokens).
struct Gemm1TSrc {
    const short* A; const short* B;
    __device__ __forceinline__ const short* operator()(int t, int h) const {
        int e = (t >> 5) & 7;
        size_t ko = (size_t)(t & 31) << 6;
        if (h & 2) return B + ((size_t)(h & 1) << 18) + ko;
        return A + ((size_t)e << 23) + ((size_t)(h & 1) << 18) + ko;
    }
};

struct Gemm2Src {
    const short* act; const short* wdt; size_t aoff, boff; int kh;
    __device__ __forceinline__ const short* operator()(int t, int h) const {
        int g = (kh << 7) + t;
        int e = (g >> 5) & 7;
        size_t ko = (size_t)(g & 31) << 6;
        if (h & 2) return wdt + ((size_t)e << 22) + boff + ((size_t)(h & 1) << 18) + ko;
        return act + ((size_t)e << 23) + aoff + ((size_t)(h & 1) << 18) + ko;
    }
};

#define PH_BAR()  __builtin_amdgcn_s_barrier()
#define PH_LGKM() do { asm volatile("s_waitcnt lgkmcnt(0)" ::: "memory"); \
                       __builtin_amdgcn_sched_barrier(0); } while (0)
#define VMW(n)    asm volatile("s_waitcnt vmcnt(" #n ")" ::: "memory")

template <int NT, int SEG, typename Src, typename Epi>
__device__ __forceinline__ void gemm_8phase(const Src& src, char* smem,
                                            f32x4 (&acc)[8][4], const Epi& epi) {
    const int tid  = threadIdx.x;
    const int lane = tid & 63;
    const int wid  = tid >> 6;
    const int wr   = wid >> 2;
    const int wcol = wid & 3;
    const int lhi  = lane >> 4;
    const int llo  = lane & 15;

    auto stage = [&](int buf, int h, const short* g) {
        char* dst = smem + buf * 65536 + h * 16384;
        {
            int c = tid, r = c >> 3, s = (c & 7) ^ (r & 7);
            async_copy16(dst + c * 16, g + (size_t)r * 2048 + s * 8);
        }
        {
            int c = tid + 512, r = c >> 3, s = (c & 7) ^ (r & 7);
            async_copy16(dst + c * 16, g + (size_t)r * 2048 + s * 8);
        }
    };
    auto ldfrag = [&](int buf, int h, int row, int slot) {
        return *(const bf16x8*)(smem + buf * 65536 + h * 16384 + row * 128 +
                                ((slot ^ (row & 7)) << 4));
    };

    stage(0, 0, src(0, 0)); stage(0, 2, src(0, 2));
    stage(0, 3, src(0, 3)); stage(0, 1, src(0, 1));
    stage(1, 0, src(1, 0)); stage(1, 2, src(1, 2)); stage(1, 3, src(1, 3));
    VMW(8);
    PH_BAR();

    bf16x8 a[4][2], b[4][2];
#pragma unroll
    for (int n = 0; n < 2; ++n) {
        int row = wcol * 32 + n * 16 + llo;
        b[n][0] = ldfrag(0, 2, row, lhi);
        b[n][1] = ldfrag(0, 2, row, 4 + lhi);
    }

    for (int t = 0; t < NT; ++t) {
        const int cur = t & 1, nxt = cur ^ 1;
        // P0
#pragma unroll
        for (int m = 0; m < 4; ++m) {
            int row = wr * 64 + m * 16 + llo;
            a[m][0] = ldfrag(cur, 0, row, lhi);
            a[m][1] = ldfrag(cur, 0, row, 4 + lhi);
        }
        if (t + 1 < NT) stage(nxt, 1, src(t + 1, 1));
        PH_BAR(); PH_LGKM();
        __builtin_amdgcn_s_setprio(1);
#pragma unroll
        for (int m = 0; m < 4; ++m)
#pragma unroll
            for (int n = 0; n < 2; ++n)
#pragma unroll
                for (int ks = 0; ks < 2; ++ks)
                    acc[m][n] = __builtin_amdgcn_mfma_f32_16x16x32_bf16(
                        a[m][ks], b[n][ks], acc[m][n], 0, 0, 0);
        __builtin_amdgcn_s_setprio(0);
        PH_BAR();
        // P1
#pragma unroll
        for (int n = 0; n < 2; ++n) {
            int row = wcol * 32 + n * 16 + llo;
            b[2 + n][0] = ldfrag(cur, 3, row, lhi);
            b[2 + n][1] = ldfrag(cur, 3, row, 4 + lhi);
        }
        if (t + 2 < NT) { stage(cur, 0, src(t + 2, 0)); VMW(10); }
        else if (t + 1 < NT) { VMW(8); }
        else { VMW(0); }
        PH_BAR(); PH_LGKM();
        __builtin_amdgcn_s_setprio(1);
#pragma unroll
        for (int m = 0; m < 4; ++m)
#pragma unroll
            for (int n = 2; n < 4; ++n)
#pragma unroll
                for (int ks = 0; ks < 2; ++ks)
                    acc[m][n] = __builtin_amdgcn_mfma_f32_16x16x32_bf16(
                        a[m][ks], b[n][ks], acc[m][n], 0, 0, 0);
        __builtin_amdgcn_s_setprio(0);
        PH_BAR();
        // P2
#pragma unroll
        for (int m = 0; m < 4; ++m) {
            int row = wr * 64 + m * 16 + llo;
            a[m][0] = ldfrag(cur, 1, row, lhi);
            a[m][1] = ldfrag(cur, 1, row, 4 + lhi);
        }
        if (t + 2 < NT) stage(cur, 2, src(t + 2, 2));
        PH_BAR(); PH_LGKM();
        __builtin_amdgcn_s_setprio(1);
#pragma unroll
        for (int m = 0; m < 4; ++m)
#pragma unroll
            for (int n = 0; n < 2; ++n)
#pragma unroll
                for (int ks = 0; ks < 2; ++ks)
                    acc[4 + m][n] = __builtin_amdgcn_mfma_f32_16x16x32_bf16(
                        a[m][ks], b[n][ks], acc[4 + m][n], 0, 0, 0);
        __builtin_amdgcn_s_setprio(0);
        PH_BAR();
        // P3
        if (t + 2 < NT) { stage(cur, 3, src(t + 2, 3)); VMW(8); }
        else if (t + 1 < NT) { VMW(2); }
        else { VMW(0); }
        PH_BAR(); PH_LGKM();
        __builtin_amdgcn_s_setprio(1);
        if (t + 1 < NT) {
#pragma unroll
            for (int n = 0; n < 2; ++n) {
                int row = wcol * 32 + n * 16 + llo;
                b[n][0] = ldfrag(nxt, 2, row, lhi);
                b[n][1] = ldfrag(nxt, 2, row, 4 + lhi);
            }
        }
#pragma unroll
        for (int m = 0; m < 4; ++m)
#pragma unroll
            for (int n = 2; n < 4; ++n)
#pragma unroll
                for (int ks = 0; ks < 2; ++ks)
                    acc[4 + m][n] = __builtin_amdgcn_mfma_f32_16x16x32_bf16(
                        a[m][ks], b[n][ks], acc[4 + m][n], 0, 0, 0);
        __builtin_amdgcn_s_setprio(0);
        PH_BAR();
        if (((t + 1) & (SEG - 1)) == 0) {
            epi(t / SEG, acc);
            if (t + 1 < NT) {
#pragma unroll
                for (int m = 0; m < 8; ++m)
#pragma unroll
                    for (int n = 0; n < 4; ++n)
                        acc[m][n] = (f32x4){0.f, 0.f, 0.f, 0.f};
            }
        }
    }
}

// ---------- GEMM1-T (persistent): output-transposed, lane-local GEGLU ----------
__global__ __launch_bounds__(512, 2) void gemm1_main(
    const short* __restrict__ xb, const short* __restrict__ wgutp,
    const float* __restrict__ bias, const float* __restrict__ rwp,
    short* __restrict__ act) {
    __shared__ __align__(16) char smem[131072];
    __shared__ float rws2[2048];   // [tloc 0..255][e 0..7]
    __shared__ float bias2[2048];  // [e 0..7][orig col-in-panel 0..255]
    const int bid = blockIdx.x;
    const int xcd = bid & 7, j = bid >> 3;
    const int t0 = (((xcd << 1) + (j >> 4)) << 8);   // token tile (B/N axis)
    const int p0 = ((j & 15) << 8);                  // gate_up row panel (A/M axis)
    const int tid  = threadIdx.x;
    const int lane = tid & 63;
    const int wid  = tid >> 6;
    const int wr = wid >> 2, wcol = wid & 3;
    const int lhi = lane >> 4, llo = lane & 15;

    ((float4*)rws2)[tid] = ((const float4*)(rwp + (size_t)t0 * 8))[tid];
    {
        int idx = tid << 2;
        int ei = idx >> 8, c = idx & 255;
        ((float4*)bias2)[tid] =
            *(const float4*)(bias + (size_t)ei * 4096 + p0 + c);
    }

    f32x4 acc[8][4];
#pragma unroll
    for (int m = 0; m < 8; ++m)
#pragma unroll
        for (int n = 0; n < 4; ++n) acc[m][n] = (f32x4){0.f, 0.f, 0.f, 0.f};

    Gemm1TSrc src{ wgutp + (size_t)p0 * 2048, xb + (size_t)t0 * 2048 };
    const int dbase = (p0 >> 1) + wr * 64;   // act dcol base for this wave

    auto epi = [&](int s, f32x4 (&ac)[8][4]) {
        int e = s & 7;
        short* acte = act + ((size_t)e << 23);
#pragma unroll
        for (int m = 0; m < 4; ++m) {
            float bg[4], bu[4];
#pragma unroll
            for (int q = 0; q < 4; ++q) {
                int jj = wr * 64 + m * 16 + (lhi << 2) + q;
                bg[q] = bias2[(e << 8) + 2 * jj];
                bu[q] = bias2[(e << 8) + 2 * jj + 1];
            }
            int dc0 = dbase + m * 16 + (lhi << 2);
#pragma unroll
            for (int n = 0; n < 4; ++n) {
                int tloc = ((n >> 1) << 7) + wcol * 32 + ((n & 1) << 4) + llo;
                float w = rws2[tloc * 8 + e];
                short4v o;
#pragma unroll
                for (int q = 0; q < 4; ++q) {
                    float g = ac[m][n][q] + bg[q];
                    float u = ac[4 + m][n][q] + bu[q];
                    g = fminf(g, GLIMIT);
                    u = fmaxf(fminf(u, GLIMIT), -GLIMIT);
                    float glu = g / (1.f + __expf(-ALPHA * g));
                    o[q] = f2bf((u + 1.f) * glu * w);
                }
                *(short4v*)(acte + (size_t)(t0 + tloc) * 2048 + dc0) = o;
            }
        }
    };
    gemm_8phase<256, 32>(src, smem, acc, epi);
}

// ---------- GEMM2: split-K over experts; kh=0 -> out, kh=1 -> partial ----------
__global__ __launch_bounds__(512, 2) void gemm2_8ph(
    const short* __restrict__ act, const short* __restrict__ wdt,
    float* __restrict__ out, float* __restrict__ part) {
    __shared__ __align__(16) char smem[131072];
    const int kh = blockIdx.z;
    int flat = blockIdx.x + (blockIdx.y << 3);
    int swz = (flat & 7) * 16 + (flat >> 3);
    const int n0 = (swz & 7) * 256;
    const int m0 = (swz >> 3) * 256;
    const int tid  = threadIdx.x;
    const int lane = tid & 63;
    const int wid  = tid >> 6;
    const int wr = wid >> 2, wcol = wid & 3;

    f32x4 acc[8][4];
#pragma unroll
    for (int m = 0; m < 8; ++m)
#pragma unroll
        for (int n = 0; n < 4; ++n) acc[m][n] = (f32x4){0.f, 0.f, 0.f, 0.f};

    Gemm2Src src{ act, wdt, (size_t)m0 * 2048, (size_t)n0 * 2048, kh };
    float* dst = (kh == 0) ? out : part;

    auto epi = [&](int, f32x4 (&ac)[8][4]) {
#pragma unroll
        for (int m = 0; m < 8; ++m) {
            int row = m0 + (m >> 2) * 128 + wr * 64 + (m & 3) * 16 + ((lane >> 4) << 2);
#pragma unroll
            for (int n = 0; n < 4; ++n) {
                int col = n0 + (n >> 1) * 128 + wcol * 32 + (n & 1) * 16 + (lane & 15);
#pragma unroll
                for (int q = 0; q < 4; ++q)
                    dst[(size_t)(row + q) * 2048 + col] = ac[m][n][q];
            }
        }
    };
    gemm_8phase<128, 128>(src, smem, acc, epi);
}

// ---------- reduce: out += partial + sum_e rw[t,e]*bd[e,h] ----------
__global__ __launch_bounds__(256) void reduce_bias(
    const float* __restrict__ p1, const float* __restrict__ rw,
    const float* __restrict__ bd, float* __restrict__ out) {
    const int t = blockIdx.x;
    const int tid = threadIdx.x;
    float rwv[8];
#pragma unroll
    for (int e = 0; e < 8; ++e) rwv[e] = rw[(size_t)t * 8 + e];
    size_t base = (size_t)t * 2048;
#pragma unroll
    for (int i = 0; i < 2; ++i) {
        int h = (tid + i * 256) * 4;
        f32x4 o = *(const f32x4*)(out + base + h);
        f32x4 p = *(const f32x4*)(p1 + base + h);
        o += p;
#pragma unroll
        for (int e = 0; e < 8; ++e) {
            f32x4 bb = *(const f32x4*)(bd + e * 2048 + h);
            o += rwv[e] * bb;
        }
        *(f32x4*)(out + base + h) = o;
    }
}

extern "C" void kernel_launch(void* const* d_in, const int* in_sizes, int n_in,
                              void* d_out, int out_size, void* d_ws, size_t ws_size,
                              hipStream_t stream) {
    const float* x   = (const float*)d_in[0];
    const float* wgu = (const float*)d_in[1];
    const float* bgu = (const float*)d_in[2];
    const float* wd  = (const float*)d_in[3];
    const float* bd  = (const float*)d_in[4];
    const float* rw  = (const float*)d_in[5];
    float* out = (float*)d_out;

    char* ws = (char*)d_ws;
    short* xb   = (short*)(ws);
    short* wgut = (short*)(ws + 16777216);
    float* p1   = (float*)(ws + 16777216);   // aliases wgut (dead after gemm1)
    short* wdt  = (short*)(ws + 150994944);
    short* actb = (short*)(ws + 218103808);

    cvt_bf16_kernel<<<8192, 256, 0, stream>>>(x, xb, 2097152);
    transpose_cvt<<<dim3(64, 32, 8), 256, 0, stream>>>(wgu, wgut, 2048, 4096, 1);
    transpose_cvt<<<dim3(32, 32, 8), 256, 0, stream>>>(wd, wdt, 2048, 2048, 0);
    gemm1_main<<<256, 512, 0, stream>>>(xb, wgut, bgu, rw, actb);
    gemm2_8ph<<<dim3(8, 16, 2), 512, 0, stream>>>(actb, wdt, out, p1);
    reduce_bias<<<4096, 256, 0, stream>>>(p1, rw, bd, out);
}